// Round 11
// baseline (83.048 us; speedup 1.0000x reference)
//
#include <hip/hip_runtime.h>

#define TPB     256
#define LSEQ    1024          // L
#define NCOL    1022          // n = L-2 (columns)
#define NROW    1021          // cumprod rows
#define NPAD    1024          // leading zeros -> no index clamp, aligned b128 reads
#define SLDS    2048          // NPAD + NCOL + tail pad
#define NCHUNK  8
#define RPC     128           // rows per chunk (last: 125)

typedef float v2f __attribute__((ext_vector_type(2)));
typedef float v4f __attribute__((ext_vector_type(4)));

__device__ __forceinline__ float clamp01(float x) {
    return fminf(fmaxf(x, 0.0f), 1.0f);          // v_med3_f32
}

// R10 structure (single-owner full-row blocks, 4 cols/thread, 2 blocks/CU),
// with NONTEMPORAL stores: discriminating probe for the remaining 17% gap
// to fill-rate (6.0 vs 7.2 TB/s). NT bypasses L2 -> if the tax was L2
// allocate/evict overhead, rate rises; if it's DRAM address-pattern
// inefficiency (or NT partial-line RMW), null/regress -> R10 is the ceiling.
// Single-owner regions keep NT partial-line writes to 2 row-edge lines per
// row (~3% transaction overhead, HBM masked writes).
__global__ __launch_bounds__(TPB) void gate_kernel(
    const float* __restrict__ score,
    const int*   __restrict__ score_idx,
    float*       __restrict__ out)
{
    __shared__ __align__(16) float sp[SLDS];

    const int bid = blockIdx.x;
    const int ch  = bid >> 6;            // chunk 0..7
    const int bd  = bid & 63;            // b*2 + d   (XCD = bd % 8)
    const int d   = bd & 1;
    const int b   = bd >> 1;
    const int tid = threadIdx.x;

    for (int i = tid; i < NPAD; i += TPB) sp[i] = 0.0f;
    if (tid < 2) sp[NPAD + NCOL + tid] = 0.0f;          // tail pad
    const int* idxRow = score_idx + b * LSEQ + 1;       // docs[b][1:]
    for (int i = tid; i < NCOL; i += TPB) {
        int src = d ? (NCOL - 1 - i) : i;
        sp[NPAD + i] = score[idxRow[src]];
    }
    __syncthreads();

    const int j = tid * 4;               // columns j..j+3 (t=255: j+2,j+3 pad)
    const float c0 = 1.0f - 10.0f * sp[NPAD + j    ];
    const float c1 = 1.0f - 10.0f * sp[NPAD + j + 1];
    const float c2 = 1.0f - 10.0f * sp[NPAD + j + 2];
    const float c3 = 1.0f - 10.0f * sp[NPAD + j + 3];

    float a0 = 1.0f, a1 = 1.0f, a2 = 1.0f, a3 = 1.0f;
    float C1 = sp[NPAD + j], C2 = sp[NPAD + j + 1], C3 = sp[NPAD + j + 2];
    int   m  = NPAD + j - 1;             // fresh-value index (col j), descending

#define STEP(X)                                                     \
    {   float _x = (X);                                             \
        float p0 = clamp01(__builtin_fmaf(_x, 10.0f, c0));          \
        float p1 = clamp01(__builtin_fmaf(C1, 10.0f, c1));          \
        float p2 = clamp01(__builtin_fmaf(C2, 10.0f, c2));          \
        float p3 = clamp01(__builtin_fmaf(C3, 10.0f, c3));          \
        a0 *= p0; a1 *= p1; a2 *= p2; a3 *= p3;                     \
        C3 = C2; C2 = C1; C1 = _x; }

    // ---------- prefix: rows [0, 128*ch), no stores ----------
    #pragma unroll 1
    for (int bt = 0; bt < ch * (RPC / 8); ++bt) {
        v4f hi = *(const v4f*)&sp[m - 3];    // 16B-aligned (NPAD=1024)
        v4f lo = *(const v4f*)&sp[m - 7];
        m -= 8;
        STEP(hi.w); STEP(hi.z); STEP(hi.y); STEP(hi.x);
        STEP(lo.w); STEP(lo.z); STEP(lo.y); STEP(lo.x);
    }

    // ---------- store loop: rows [r0, r1) ----------
    const int r0 = ch * RPC;
    const int nrows = (r0 + RPC < NROW) ? RPC : (NROW - r0);   // 128 or 125
    const bool half = (tid == TPB - 1);  // last thread: only 2 real columns

    float* outp = out + (size_t)bd * NROW * NCOL + (size_t)r0 * NCOL + j;

#define EMIT                                                        \
    {   if (half) { v2f w2; w2.x = a0; w2.y = a1;                   \
                    __builtin_nontemporal_store(w2, (v2f*)outp); }  \
        else      { v4f w; w.x = a0; w.y = a1; w.z = a2; w.w = a3;  \
                    __builtin_nontemporal_store(w, (v4f*)outp); }   \
        outp += NCOL; }

    #pragma unroll 1
    for (int bt = 0; bt < nrows / 8; ++bt) {
        v4f hi = *(const v4f*)&sp[m - 3];
        v4f lo = *(const v4f*)&sp[m - 7];
        m -= 8;
        STEP(hi.w); EMIT; STEP(hi.z); EMIT; STEP(hi.y); EMIT; STEP(hi.x); EMIT;
        STEP(lo.w); EMIT; STEP(lo.z); EMIT; STEP(lo.y); EMIT; STEP(lo.x); EMIT;
    }
    #pragma unroll 1
    for (int r = nrows & ~7; r < nrows; ++r) {    // tail: 5 rows, last chunk
        float x = sp[m]; --m;
        STEP(x); EMIT;
    }
#undef STEP
#undef EMIT
}

extern "C" void kernel_launch(void* const* d_in, const int* in_sizes, int n_in,
                              void* d_out, int out_size, void* d_ws, size_t ws_size,
                              hipStream_t stream)
{
    const float* score = (const float*)d_in[0];
    const int*   sidx  = (const int*)d_in[1];
    float*       out   = (float*)d_out;

    const int B = in_sizes[0] / LSEQ;    // 32
    dim3 grid(B * 2 * NCHUNK), block(TPB);   // 512 blocks x 256 threads
    gate_kernel<<<grid, block, 0, stream>>>(score, sidx, out);
}

// Round 12
// 44.353 us; speedup vs baseline: 1.8724x; 1.8724x over previous
//
#include <hip/hip_runtime.h>

#define TPB     256
#define LSEQ    1024          // L
#define NCOL    1022          // n = L-2 (columns)
#define NROW    1021          // cumprod rows
#define NPAD    1024          // leading zeros -> no index clamp, aligned b128 reads
#define SLDS    2048          // NPAD + NCOL + tail pad
#define NCHUNK  8
#define RPC     128           // rows per chunk (last: 125)

typedef float v2f __attribute__((ext_vector_type(2)));
typedef float v4f __attribute__((ext_vector_type(4)));

__device__ __forceinline__ float clamp01(float x) {
    return fminf(fmaxf(x, 0.0f), 1.0f);          // v_med3_f32
}

// FINAL (R10 revert): single-owner full-row blocks, 4 cols/thread, float4
// stores through L2 (NT probe in R11 regressed 2x -> L2 write-merge is
// essential for this 4088B-row-stride layout). 512 blocks = 2 blocks/CU.
// Chunk regions contiguous + 128B-aligned (128*4088 % 128 == 0) -> no
// cross-block split lines; bid = ch*64 + bd keeps all chunks of a matrix
// on one XCD (XCD = bd % 8). Serial prefix recompute is hidden under the
// co-resident block's stores. Measured 44.5us = 83% of the achievable
// fill-rate on this buffer (37.2us); residual is partial-line handling
// forced by the fixed output layout.
__global__ __launch_bounds__(TPB) void gate_kernel(
    const float* __restrict__ score,
    const int*   __restrict__ score_idx,
    float*       __restrict__ out)
{
    __shared__ __align__(16) float sp[SLDS];

    const int bid = blockIdx.x;
    const int ch  = bid >> 6;            // chunk 0..7
    const int bd  = bid & 63;            // b*2 + d   (XCD = bd % 8)
    const int d   = bd & 1;
    const int b   = bd >> 1;
    const int tid = threadIdx.x;

    for (int i = tid; i < NPAD; i += TPB) sp[i] = 0.0f;
    if (tid < 2) sp[NPAD + NCOL + tid] = 0.0f;          // tail pad
    const int* idxRow = score_idx + b * LSEQ + 1;       // docs[b][1:]
    for (int i = tid; i < NCOL; i += TPB) {
        int src = d ? (NCOL - 1 - i) : i;
        sp[NPAD + i] = score[idxRow[src]];
    }
    __syncthreads();

    const int j = tid * 4;               // columns j..j+3 (t=255: j+2,j+3 pad)
    const float c0 = 1.0f - 10.0f * sp[NPAD + j    ];
    const float c1 = 1.0f - 10.0f * sp[NPAD + j + 1];
    const float c2 = 1.0f - 10.0f * sp[NPAD + j + 2];
    const float c3 = 1.0f - 10.0f * sp[NPAD + j + 3];

    float a0 = 1.0f, a1 = 1.0f, a2 = 1.0f, a3 = 1.0f;
    float C1 = sp[NPAD + j], C2 = sp[NPAD + j + 1], C3 = sp[NPAD + j + 2];
    int   m  = NPAD + j - 1;             // fresh-value index (col j), descending

#define STEP(X)                                                     \
    {   float _x = (X);                                             \
        float p0 = clamp01(__builtin_fmaf(_x, 10.0f, c0));          \
        float p1 = clamp01(__builtin_fmaf(C1, 10.0f, c1));          \
        float p2 = clamp01(__builtin_fmaf(C2, 10.0f, c2));          \
        float p3 = clamp01(__builtin_fmaf(C3, 10.0f, c3));          \
        a0 *= p0; a1 *= p1; a2 *= p2; a3 *= p3;                     \
        C3 = C2; C2 = C1; C1 = _x; }

    // ---------- prefix: rows [0, 128*ch), no stores ----------
    #pragma unroll 1
    for (int bt = 0; bt < ch * (RPC / 8); ++bt) {
        v4f hi = *(const v4f*)&sp[m - 3];    // 16B-aligned (NPAD=1024)
        v4f lo = *(const v4f*)&sp[m - 7];
        m -= 8;
        STEP(hi.w); STEP(hi.z); STEP(hi.y); STEP(hi.x);
        STEP(lo.w); STEP(lo.z); STEP(lo.y); STEP(lo.x);
    }

    // ---------- store loop: rows [r0, r1) ----------
    const int r0 = ch * RPC;
    const int nrows = (r0 + RPC < NROW) ? RPC : (NROW - r0);   // 128 or 125
    const bool half = (tid == TPB - 1);  // last thread: only 2 real columns

    float* outp = out + (size_t)bd * NROW * NCOL + (size_t)r0 * NCOL + j;

#define EMIT                                                        \
    {   if (half) { v2f w2; w2.x = a0; w2.y = a1; *(v2f*)outp = w2; } \
        else      { v4f w; w.x = a0; w.y = a1; w.z = a2; w.w = a3;  \
                    *(v4f*)outp = w; }                              \
        outp += NCOL; }

    #pragma unroll 1
    for (int bt = 0; bt < nrows / 8; ++bt) {
        v4f hi = *(const v4f*)&sp[m - 3];
        v4f lo = *(const v4f*)&sp[m - 7];
        m -= 8;
        STEP(hi.w); EMIT; STEP(hi.z); EMIT; STEP(hi.y); EMIT; STEP(hi.x); EMIT;
        STEP(lo.w); EMIT; STEP(lo.z); EMIT; STEP(lo.y); EMIT; STEP(lo.x); EMIT;
    }
    #pragma unroll 1
    for (int r = nrows & ~7; r < nrows; ++r) {    // tail: 5 rows, last chunk
        float x = sp[m]; --m;
        STEP(x); EMIT;
    }
#undef STEP
#undef EMIT
}

extern "C" void kernel_launch(void* const* d_in, const int* in_sizes, int n_in,
                              void* d_out, int out_size, void* d_ws, size_t ws_size,
                              hipStream_t stream)
{
    const float* score = (const float*)d_in[0];
    const int*   sidx  = (const int*)d_in[1];
    float*       out   = (float*)d_out;

    const int B = in_sizes[0] / LSEQ;    // 32
    dim3 grid(B * 2 * NCHUNK), block(TPB);   // 512 blocks x 256 threads
    gate_kernel<<<grid, block, 0, stream>>>(score, sidx, out);
}